// Round 13
// baseline (364.055 us; speedup 1.0000x reference)
//
#include <hip/hip_runtime.h>
#include <hip/hip_bf16.h>
#include <math.h>

#define BB   4
#define CC   32
#define HH   120
#define WW   160
#define NH_  8
#define HD   20
#define HDP  32            // head dim padded to 32 (zeros) for K=32 MFMA
#define NN   3840          // sequence length (C*H)
#define ROWS 3840
#define NBH  32            // B * NH
#define LOG2E 1.44269504088896f

typedef float f32x4  __attribute__((ext_vector_type(4)));
typedef float f32x16 __attribute__((ext_vector_type(16)));
typedef short s16x8 __attribute__((ext_vector_type(8)));
typedef short s16x4 __attribute__((ext_vector_type(4)));
typedef unsigned u32x4 __attribute__((ext_vector_type(4)));

static __device__ __forceinline__ unsigned short f2bf(float x) {
    return __builtin_bit_cast(unsigned short, __float2bfloat16(x));
}
static __device__ __forceinline__ float bf2f(unsigned short u) {
    unsigned v = ((unsigned)u) << 16;
    return __builtin_bit_cast(float, v);
}
static __device__ __forceinline__ float exp2fast(float x) {
#if defined(__has_builtin) && __has_builtin(__builtin_amdgcn_exp2f)
    return __builtin_amdgcn_exp2f(x);
#else
    float r; asm("v_exp_f32 %0, %1" : "=v"(r) : "v"(x)); return r;
#endif
}

// round-half-up bf16 pair pack (BUILTIN-ONLY; validated R5/R9-R12).
// returns dword: lo16 = bf16(a), hi16 = bf16(b).
static __device__ __forceinline__ unsigned pack2(float a, float b) {
    unsigned ua = __builtin_bit_cast(unsigned, a) + 0x8000u;
    unsigned ub = __builtin_bit_cast(unsigned, b) + 0x8000u;
#if defined(__has_builtin) && __has_builtin(__builtin_amdgcn_perm)
    return __builtin_amdgcn_perm(ub, ua, 0x07060302u);
#else
    return (ua >> 16) | (ub & 0xffff0000u);
#endif
}

// exp2 four lanes then pack (legacy 16x16 path, used by nothing hot now)
static __device__ __forceinline__ s16x4 exp4_pack(f32x4 e) {
    uint2 w;
    w.x = pack2(exp2fast(e[0]), exp2fast(e[1]));
    w.y = pack2(exp2fast(e[2]), exp2fast(e[3]));
    return __builtin_bit_cast(s16x4, w);
}

static __device__ __forceinline__ f32x4 mfma32(s16x8 a, s16x8 b, f32x4 c) {
    return __builtin_amdgcn_mfma_f32_16x16x32_bf16(a, b, c, 0, 0, 0);
}
static __device__ __forceinline__ f32x16 mfma32x32(s16x8 a, s16x8 b, f32x16 c) {
    return __builtin_amdgcn_mfma_f32_32x32x16_bf16(a, b, c, 0, 0, 0);
}
static __device__ __forceinline__ s16x8 cat44(s16x4 a, s16x4 b) {
    s16x8 r;
    r[0]=a[0]; r[1]=a[1]; r[2]=a[2]; r[3]=a[3];
    r[4]=b[0]; r[5]=b[1]; r[6]=b[2]; r[7]=b[3];
    return r;
}

// ---------------- W prep: f32 -> bf16 [o][k]; Wq pre-scaled by log2(e) ----
__global__ __launch_bounds__(256)
void wprep_kernel(const float* __restrict__ Wq, const float* __restrict__ Wk,
                  const float* __restrict__ Wv,
                  unsigned short* __restrict__ wqb, unsigned short* __restrict__ wkb,
                  unsigned short* __restrict__ wvb)
{
    int i = blockIdx.x*256 + threadIdx.x;
    if (i < WW*WW) {
        wqb[i] = f2bf(Wq[i] * LOG2E);
        wkb[i] = f2bf(Wk[i]);
        wvb[i] = f2bf(Wv[i]);
    }
}

// ---------------- Projection via MFMA (no LDS) ---------------------------
__global__ __launch_bounds__(256)
void proj_mfma_kernel(const float* __restrict__ x,
                      const unsigned short* __restrict__ wqb,
                      const unsigned short* __restrict__ wkb,
                      const unsigned short* __restrict__ wvb,
                      const float* __restrict__ bq, const float* __restrict__ bk,
                      const float* __restrict__ bv,
                      unsigned short* __restrict__ qt, unsigned short* __restrict__ kt,
                      unsigned short* __restrict__ vb)
{
    const int tid  = threadIdx.x;
    const int wv   = tid >> 6;
    const int lane = tid & 63;
    const int g = lane >> 4, c = lane & 15;
    const int r0 = blockIdx.x*64 + wv*16;

    s16x8 A[5];
    const float* xrow = x + (size_t)(r0 + c)*WW;
    #pragma unroll
    for (int s = 0; s < 5; ++s) {
        float4 v0 = *(const float4*)(xrow + s*32 + g*8);
        float4 v1 = *(const float4*)(xrow + s*32 + g*8 + 4);
        s16x8 a;
        a[0]=(short)f2bf(v0.x); a[1]=(short)f2bf(v0.y);
        a[2]=(short)f2bf(v0.z); a[3]=(short)f2bf(v0.w);
        a[4]=(short)f2bf(v1.x); a[5]=(short)f2bf(v1.y);
        a[6]=(short)f2bf(v1.z); a[7]=(short)f2bf(v1.w);
        A[s] = a;
    }

    size_t baseqk[4], basev[4];
    #pragma unroll
    for (int rr = 0; rr < 4; ++rr) {
        int R  = r0 + g*4 + rr;
        int b  = R / ROWS;
        int r  = R % ROWS;
        int nh = r / 480;
        int rm = r % 480;
        int d  = rm / 24;
        int n1 = rm % 24;
        int bh = b*NH_ + nh;
        baseqk[rr] = ((size_t)bh*NN + n1*160)*HDP + d;
        basev[rr]  = ((size_t)bh*HD + d)*NN + n1*160;
    }

    const f32x4 zero4 = {0.f, 0.f, 0.f, 0.f};
    for (int nt = 0; nt < 10; ++nt) {
        const size_t wbase = (size_t)(nt*16 + c)*WW;
        f32x4 aq = zero4, ak = zero4, av = zero4;
        #pragma unroll
        for (int s = 0; s < 5; ++s) {
            s16x8 Bq = *(const s16x8*)(wqb + wbase + s*32 + g*8);
            aq = mfma32(A[s], Bq, aq);
            s16x8 Bk = *(const s16x8*)(wkb + wbase + s*32 + g*8);
            ak = mfma32(A[s], Bk, ak);
            s16x8 Bv = *(const s16x8*)(wvb + wbase + s*32 + g*8);
            av = mfma32(A[s], Bv, av);
        }
        const int o = nt*16 + c;
        const float bqv = bq[o]*LOG2E, bkv = bk[o], bvv = bv[o];
        #pragma unroll
        for (int rr = 0; rr < 4; ++rr) {
            qt[baseqk[rr] + (size_t)o*HDP] = f2bf(aq[rr] + bqv);
            kt[baseqk[rr] + (size_t)o*HDP] = f2bf(ak[rr] + bkv);
            vb[basev[rr] + o]              = f2bf(av[rr] + bvv);
        }
    }
}

// ---------------- Pass 1: zinv[m] = 1 / sum_n exp2(E[m,n]) ---------------
// R12-exact (passing): 1920 blocks, XCD swizzle, 1-deep K prefetch.
__global__ __launch_bounds__(256, 4)
void zinv_kernel(const unsigned short* __restrict__ qt,
                 const unsigned short* __restrict__ kt,
                 float* __restrict__ zinv)
{
    __shared__ float zred[4][64];
    const int blk  = ((int)blockIdx.x & 7) * (NBH*(NN/64)/8) + ((int)blockIdx.x >> 3);
    const int bh   = blk / (NN/64);
    const int m0   = (blk % (NN/64)) * 64;
    const int tid  = threadIdx.x;
    const int wv   = tid >> 6;
    const int lane = tid & 63;
    const int g = lane >> 4, c = lane & 15;

    s16x8 qa[4];
    #pragma unroll
    for (int ms = 0; ms < 4; ++ms)
        qa[ms] = *(const s16x8*)(qt + ((size_t)bh*NN + m0 + ms*16 + c)*HDP + g*8);

    const f32x4 zero4 = {0.f, 0.f, 0.f, 0.f};
    f32x4 z[4];
    #pragma unroll
    for (int ms = 0; ms < 4; ++ms) z[ms] = zero4;

    const unsigned short* kbase = kt + (size_t)bh*NN*HDP;
    const int nbeg = wv * (NN/4);
    const int nend = nbeg + NN/4;

    s16x8 kb0 = *(const s16x8*)(kbase + (size_t)(nbeg +      c)*HDP + g*8);
    s16x8 kb1 = *(const s16x8*)(kbase + (size_t)(nbeg + 16 + c)*HDP + g*8);

    for (int n = nbeg; n < nend - 32; n += 32) {
        s16x8 nk0 = *(const s16x8*)(kbase + (size_t)(n + 32 +      c)*HDP + g*8);
        s16x8 nk1 = *(const s16x8*)(kbase + (size_t)(n + 48 +      c)*HDP + g*8);
        #pragma unroll
        for (int ms = 0; ms < 4; ++ms) {
            f32x4 e0 = mfma32(qa[ms], kb0, zero4);
            f32x4 e1 = mfma32(qa[ms], kb1, zero4);
            #pragma unroll
            for (int rr = 0; rr < 4; ++rr)
                z[ms][rr] += exp2fast(e0[rr]) + exp2fast(e1[rr]);
        }
        kb0 = nk0; kb1 = nk1;
    }
    #pragma unroll
    for (int ms = 0; ms < 4; ++ms) {
        f32x4 e0 = mfma32(qa[ms], kb0, zero4);
        f32x4 e1 = mfma32(qa[ms], kb1, zero4);
        #pragma unroll
        for (int rr = 0; rr < 4; ++rr)
            z[ms][rr] += exp2fast(e0[rr]) + exp2fast(e1[rr]);
    }

    #pragma unroll
    for (int ms = 0; ms < 4; ++ms) {
        #pragma unroll
        for (int rr = 0; rr < 4; ++rr) {
            float v = z[ms][rr];
            v += __shfl_xor(v, 1);
            v += __shfl_xor(v, 2);
            v += __shfl_xor(v, 4);
            v += __shfl_xor(v, 8);
            if (c == 0) zred[wv][ms*16 + g*4 + rr] = v;
        }
    }
    __syncthreads();
    if (tid < 64) {
        float s = zred[0][tid] + zred[1][tid] + zred[2][tid] + zred[3][tid];
        zinv[(size_t)bh*NN + m0 + tid] = 1.0f / s;
    }
}

// ---------------- vzb[bh][dp][m] = bf16(v[dp][m] * zinv[m]), pad rows 0 --
__global__ __launch_bounds__(256)
void vz_kernel(const unsigned short* __restrict__ vb,
               const float* __restrict__ zinv,
               unsigned short* __restrict__ vzb)
{
    size_t idx = (size_t)blockIdx.x*256 + threadIdx.x;   // over NBH*HDP*NN
    int m  = (int)(idx % NN);
    int t  = (int)(idx / NN);
    int dp = t % HDP;
    int bh = t / HDP;
    float val = 0.f;
    if (dp < HD)
        val = bf2f(vb[((size_t)bh*HD + dp)*NN + m]) * zinv[(size_t)bh*NN + m];
    vzb[idx] = f2bf(val);
}

// ---------------- Pass 2: out = Vz * exp2(Q^T K), 32x32 MFMA -------------
// R13 rewrite. Block = 32 n-cols; 4 waves split m (NN/4 each, 30 steps of
// 32); LDS f32x16 reduce; XCD swizzle. Per step: 2 E-mfma(32x32x16, K=16x2)
// -> 16 exp2 -> 8 pack2 -> 2 PV-mfma. PV K-slot permutation trick: feed P in
// its natural D-frag order and gather Vz with the SAME m-permutation
// em(g2,j) = (j&3)+8*(j>>2)+4*g2  (dot product invariant under K-perm).
__global__ __launch_bounds__(256, 4)
void attn_out_kernel(const unsigned short* __restrict__ qt,
                     const unsigned short* __restrict__ kt,
                     const unsigned short* __restrict__ vzb,
                     float* __restrict__ y)
{
    __shared__ float red[3][16][64];   // 12 KB
    // bijective swizzle: grid 3840 (%8==0), chunk 480 per XCD
    const int blk  = ((int)blockIdx.x & 7) * (NBH*(NN/32)/8) + ((int)blockIdx.x >> 3);
    const int bh   = blk / (NN/32);
    const int n0   = (blk % (NN/32)) * 32;
    const int tid  = threadIdx.x;
    const int wv   = tid >> 6;
    const int lane = tid & 63;
    const int g2 = lane >> 5, c2 = lane & 31;
    const int b = bh >> 3, nh = bh & 7;

    const unsigned short* qb  = qt  + (size_t)bh*NN*HDP;
    const unsigned short* kbp = kt  + (size_t)bh*NN*HDP;
    const unsigned short* vp  = vzb + (size_t)bh*HDP*NN;

    // K B-frags (loop-invariant): B[k=d][col=n0+c2], d = g2*8+j (+16)
    const s16x8 kbA = *(const s16x8*)(kbp + (size_t)(n0 + c2)*HDP + g2*8);
    const s16x8 kbB = *(const s16x8*)(kbp + (size_t)(n0 + c2)*HDP + g2*8 + 16);

    f32x16 acc;
    #pragma unroll
    for (int i = 0; i < 16; ++i) acc[i] = 0.f;
    f32x16 zero16;
    #pragma unroll
    for (int i = 0; i < 16; ++i) zero16[i] = 0.f;

    const int mbeg = wv * (NN/4);           // 960 m = 30 steps of 32
    const int mend = mbeg + NN/4;
    const unsigned short* vrow = vp + (size_t)c2*NN;   // Vz row d = c2

    // prologue: step-0 fragments
    s16x8 qaA = *(const s16x8*)(qb + (size_t)(mbeg + c2)*HDP + g2*8);
    s16x8 qaB = *(const s16x8*)(qb + (size_t)(mbeg + c2)*HDP + g2*8 + 16);
    s16x4 vz0 = *(const s16x4*)(vrow + mbeg +      4*g2);
    s16x4 vz1 = *(const s16x4*)(vrow + mbeg +  8 + 4*g2);
    s16x4 vz2 = *(const s16x4*)(vrow + mbeg + 16 + 4*g2);
    s16x4 vz3 = *(const s16x4*)(vrow + mbeg + 24 + 4*g2);

    for (int m0 = mbeg; m0 < mend - 32; m0 += 32) {
        const int m1 = m0 + 32;
        // prefetch next step
        s16x8 nqaA = *(const s16x8*)(qb + (size_t)(m1 + c2)*HDP + g2*8);
        s16x8 nqaB = *(const s16x8*)(qb + (size_t)(m1 + c2)*HDP + g2*8 + 16);
        s16x4 nvz0 = *(const s16x4*)(vrow + m1 +      4*g2);
        s16x4 nvz1 = *(const s16x4*)(vrow + m1 +  8 + 4*g2);
        s16x4 nvz2 = *(const s16x4*)(vrow + m1 + 16 + 4*g2);
        s16x4 nvz3 = *(const s16x4*)(vrow + m1 + 24 + 4*g2);

        // E tile (32m x 32n), K = d = 32 via 2 accumulating mfmas
        f32x16 e = mfma32x32(qaA, kbA, zero16);
        e = mfma32x32(qaB, kbB, e);
        // P = exp2(E), packed in natural D-frag order
        u32x4 w1, w2;
        w1[0] = pack2(exp2fast(e[0]),  exp2fast(e[1]));
        w1[1] = pack2(exp2fast(e[2]),  exp2fast(e[3]));
        w1[2] = pack2(exp2fast(e[4]),  exp2fast(e[5]));
        w1[3] = pack2(exp2fast(e[6]),  exp2fast(e[7]));
        w2[0] = pack2(exp2fast(e[8]),  exp2fast(e[9]));
        w2[1] = pack2(exp2fast(e[10]), exp2fast(e[11]));
        w2[2] = pack2(exp2fast(e[12]), exp2fast(e[13]));
        w2[3] = pack2(exp2fast(e[14]), exp2fast(e[15]));
        s16x8 B1 = __builtin_bit_cast(s16x8, w1);
        s16x8 B2 = __builtin_bit_cast(s16x8, w2);
        // PV: A gathered with the same em() permutation as P's natural order
        acc = mfma32x32(cat44(vz0, vz1), B1, acc);
        acc = mfma32x32(cat44(vz2, vz3), B2, acc);

        qaA = nqaA; qaB = nqaB;
        vz0 = nvz0; vz1 = nvz1; vz2 = nvz2; vz3 = nvz3;
    }
    {   // epilogue: last step
        f32x16 e = mfma32x32(qaA, kbA, zero16);
        e = mfma32x32(qaB, kbB, e);
        u32x4 w1, w2;
        w1[0] = pack2(exp2fast(e[0]),  exp2fast(e[1]));
        w1[1] = pack2(exp2fast(e[2]),  exp2fast(e[3]));
        w1[2] = pack2(exp2fast(e[4]),  exp2fast(e[5]));
        w1[3] = pack2(exp2fast(e[6]),  exp2fast(e[7]));
        w2[0] = pack2(exp2fast(e[8]),  exp2fast(e[9]));
        w2[1] = pack2(exp2fast(e[10]), exp2fast(e[11]));
        w2[2] = pack2(exp2fast(e[12]), exp2fast(e[13]));
        w2[3] = pack2(exp2fast(e[14]), exp2fast(e[15]));
        acc = mfma32x32(cat44(vz0, vz1), __builtin_bit_cast(s16x8, w1), acc);
        acc = mfma32x32(cat44(vz2, vz3), __builtin_bit_cast(s16x8, w2), acc);
    }

    float* af = (float*)&acc;   // 16 contiguous f32
    if (wv > 0) {
        #pragma unroll
        for (int j = 0; j < 16; ++j) red[wv-1][j][lane] = af[j];
    }
    __syncthreads();
    if (wv == 0) {
        #pragma unroll
        for (int j = 0; j < 16; ++j)
            af[j] += red[0][j][lane] + red[1][j][lane] + red[2][j][lane];
        float* yb = y + (size_t)b * CC * HH * WW;
        // D layout: row d = (reg&3)+8*(reg>>2)+4*g2, col n = n0+c2
        #pragma unroll
        for (int r = 0; r < 16; ++r) {
            int dd = (r & 3) + 8*(r >> 2) + 4*g2;
            if (dd < HD)
                yb[(size_t)(dd*NH_ + nh)*NN + n0 + c2] = acc[r];
        }
    }
}

extern "C" void kernel_launch(void* const* d_in, const int* in_sizes, int n_in,
                              void* d_out, int out_size, void* d_ws, size_t ws_size,
                              hipStream_t stream)
{
    const float* x  = (const float*)d_in[0];
    const float* Wq = (const float*)d_in[1];
    const float* bq = (const float*)d_in[2];
    const float* Wk = (const float*)d_in[3];
    const float* bk = (const float*)d_in[4];
    const float* Wv = (const float*)d_in[5];
    const float* bv = (const float*)d_in[6];
    float* y = (float*)d_out;

    const size_t QT_E = (size_t)NBH * NN * HDP;      // 3,932,160 bf16
    unsigned short* qt  = (unsigned short*)d_ws;
    unsigned short* kt  = qt + QT_E;
    unsigned short* vb  = kt + QT_E;
    unsigned short* vzb = vb + (size_t)NBH * HD * NN;
    float*          zinv = (float*)(vzb + QT_E);
    unsigned short* wqb = (unsigned short*)(zinv + (size_t)NBH*NN);
    unsigned short* wkb = wqb + WW*WW;
    unsigned short* wvb = wkb + WW*WW;               // total ~29.2 MB

    hipMemsetAsync(qt, 0, 2 * QT_E * sizeof(unsigned short), stream);

    wprep_kernel<<<dim3((WW*WW + 255)/256), dim3(256), 0, stream>>>(
        Wq, Wk, Wv, wqb, wkb, wvb);
    proj_mfma_kernel<<<dim3(BB*ROWS/64), dim3(256), 0, stream>>>(
        x, wqb, wkb, wvb, bq, bk, bv, qt, kt, vb);
    zinv_kernel<<<dim3(NBH*(NN/64)), dim3(256), 0, stream>>>(qt, kt, zinv);
    vz_kernel<<<dim3((NBH*HDP*NN)/256), dim3(256), 0, stream>>>(vb, zinv, vzb);
    attn_out_kernel<<<dim3(NBH*(NN/32)), dim3(256), 0, stream>>>(qt, kt, vzb, y);
}

// Round 14
// 252.865 us; speedup vs baseline: 1.4397x; 1.4397x over previous
//
#include <hip/hip_runtime.h>
#include <hip/hip_bf16.h>
#include <math.h>

#define BB   4
#define CC   32
#define HH   120
#define WW   160
#define NH_  8
#define HD   20
#define HDP  32            // head dim padded to 32 (zeros) for K=32 MFMA
#define NN   3840          // sequence length (C*H)
#define ROWS 3840
#define NBH  32            // B * NH
#define LOG2E 1.44269504088896f

typedef float f32x4 __attribute__((ext_vector_type(4)));
typedef short s16x8 __attribute__((ext_vector_type(8)));
typedef short s16x4 __attribute__((ext_vector_type(4)));

static __device__ __forceinline__ unsigned short f2bf(float x) {
    return __builtin_bit_cast(unsigned short, __float2bfloat16(x));
}
static __device__ __forceinline__ float bf2f(unsigned short u) {
    unsigned v = ((unsigned)u) << 16;
    return __builtin_bit_cast(float, v);
}
static __device__ __forceinline__ float exp2fast(float x) {
#if defined(__has_builtin) && __has_builtin(__builtin_amdgcn_exp2f)
    return __builtin_amdgcn_exp2f(x);
#else
    float r; asm("v_exp_f32 %0, %1" : "=v"(r) : "v"(x)); return r;
#endif
}

// exp2 four lanes then pack to bf16 (round-half-up) as an s16x4 B-frag.
// BUILTIN-ONLY pack — validated R5/R9-R12. Do NOT use the cvt_pk inline-asm
// variant (R7/R8 corruption in unrolled loops).
static __device__ __forceinline__ s16x4 exp4_pack(f32x4 e) {
    unsigned u0 = __builtin_bit_cast(unsigned, exp2fast(e[0])) + 0x8000u;
    unsigned u1 = __builtin_bit_cast(unsigned, exp2fast(e[1])) + 0x8000u;
    unsigned u2 = __builtin_bit_cast(unsigned, exp2fast(e[2])) + 0x8000u;
    unsigned u3 = __builtin_bit_cast(unsigned, exp2fast(e[3])) + 0x8000u;
    uint2 w;
#if defined(__has_builtin) && __has_builtin(__builtin_amdgcn_perm)
    w.x = __builtin_amdgcn_perm(u1, u0, 0x07060302u);
    w.y = __builtin_amdgcn_perm(u3, u2, 0x07060302u);
#else
    w.x = (u0 >> 16) | (u1 & 0xffff0000u);
    w.y = (u2 >> 16) | (u3 & 0xffff0000u);
#endif
    return __builtin_bit_cast(s16x4, w);
}

#if defined(__has_builtin)
#if __has_builtin(__builtin_amdgcn_mfma_f32_16x16x16bf16_1k)
#define HAVE_MFMA16_1K 1
#endif
#endif

static __device__ __forceinline__ f32x4 mfma16(s16x4 a, s16x4 b, f32x4 c) {
#ifdef HAVE_MFMA16_1K
    return __builtin_amdgcn_mfma_f32_16x16x16bf16_1k(a, b, c, 0, 0, 0);
#else
    asm volatile("v_mfma_f32_16x16x16_bf16 %0, %1, %2, %0" : "+v"(c) : "v"(a), "v"(b));
    return c;
#endif
}
static __device__ __forceinline__ f32x4 mfma32(s16x8 a, s16x8 b, f32x4 c) {
    return __builtin_amdgcn_mfma_f32_16x16x32_bf16(a, b, c, 0, 0, 0);
}

// ---------------- W prep: f32 -> bf16 [o][k]; Wq pre-scaled by log2(e) ----
__global__ __launch_bounds__(256)
void wprep_kernel(const float* __restrict__ Wq, const float* __restrict__ Wk,
                  const float* __restrict__ Wv,
                  unsigned short* __restrict__ wqb, unsigned short* __restrict__ wkb,
                  unsigned short* __restrict__ wvb)
{
    int i = blockIdx.x*256 + threadIdx.x;
    if (i < WW*WW) {
        wqb[i] = f2bf(Wq[i] * LOG2E);
        wkb[i] = f2bf(Wk[i]);
        wvb[i] = f2bf(Wv[i]);
    }
}

// ---------------- Projection via MFMA (no LDS) ---------------------------
__global__ __launch_bounds__(256)
void proj_mfma_kernel(const float* __restrict__ x,
                      const unsigned short* __restrict__ wqb,
                      const unsigned short* __restrict__ wkb,
                      const unsigned short* __restrict__ wvb,
                      const float* __restrict__ bq, const float* __restrict__ bk,
                      const float* __restrict__ bv,
                      unsigned short* __restrict__ qt, unsigned short* __restrict__ kt,
                      unsigned short* __restrict__ vb)
{
    const int tid  = threadIdx.x;
    const int wv   = tid >> 6;
    const int lane = tid & 63;
    const int g = lane >> 4, c = lane & 15;
    const int r0 = blockIdx.x*64 + wv*16;

    s16x8 A[5];
    const float* xrow = x + (size_t)(r0 + c)*WW;
    #pragma unroll
    for (int s = 0; s < 5; ++s) {
        float4 v0 = *(const float4*)(xrow + s*32 + g*8);
        float4 v1 = *(const float4*)(xrow + s*32 + g*8 + 4);
        s16x8 a;
        a[0]=(short)f2bf(v0.x); a[1]=(short)f2bf(v0.y);
        a[2]=(short)f2bf(v0.z); a[3]=(short)f2bf(v0.w);
        a[4]=(short)f2bf(v1.x); a[5]=(short)f2bf(v1.y);
        a[6]=(short)f2bf(v1.z); a[7]=(short)f2bf(v1.w);
        A[s] = a;
    }

    size_t baseqk[4], basev[4];
    #pragma unroll
    for (int rr = 0; rr < 4; ++rr) {
        int R  = r0 + g*4 + rr;
        int b  = R / ROWS;
        int r  = R % ROWS;
        int nh = r / 480;
        int rm = r % 480;
        int d  = rm / 24;
        int n1 = rm % 24;
        int bh = b*NH_ + nh;
        baseqk[rr] = ((size_t)bh*NN + n1*160)*HDP + d;
        basev[rr]  = ((size_t)bh*HD + d)*NN + n1*160;
    }

    const f32x4 zero4 = {0.f, 0.f, 0.f, 0.f};
    for (int nt = 0; nt < 10; ++nt) {
        const size_t wbase = (size_t)(nt*16 + c)*WW;
        f32x4 aq = zero4, ak = zero4, av = zero4;
        #pragma unroll
        for (int s = 0; s < 5; ++s) {
            s16x8 Bq = *(const s16x8*)(wqb + wbase + s*32 + g*8);
            aq = mfma32(A[s], Bq, aq);
            s16x8 Bk = *(const s16x8*)(wkb + wbase + s*32 + g*8);
            ak = mfma32(A[s], Bk, ak);
            s16x8 Bv = *(const s16x8*)(wvb + wbase + s*32 + g*8);
            av = mfma32(A[s], Bv, av);
        }
        const int o = nt*16 + c;
        const float bqv = bq[o]*LOG2E, bkv = bk[o], bvv = bv[o];
        #pragma unroll
        for (int rr = 0; rr < 4; ++rr) {
            qt[baseqk[rr] + (size_t)o*HDP] = f2bf(aq[rr] + bqv);
            kt[baseqk[rr] + (size_t)o*HDP] = f2bf(ak[rr] + bkv);
            vb[basev[rr] + o]              = f2bf(av[rr] + bvv);
        }
    }
}

// ---------------- Pass 1: zinv[m] = 1 / sum_n exp2(E[m,n]) ---------------
// R12-exact (passing): 1920 blocks, XCD swizzle, 1-deep K prefetch.
__global__ __launch_bounds__(256, 4)
void zinv_kernel(const unsigned short* __restrict__ qt,
                 const unsigned short* __restrict__ kt,
                 float* __restrict__ zinv)
{
    __shared__ float zred[4][64];
    const int blk  = ((int)blockIdx.x & 7) * (NBH*(NN/64)/8) + ((int)blockIdx.x >> 3);
    const int bh   = blk / (NN/64);
    const int m0   = (blk % (NN/64)) * 64;
    const int tid  = threadIdx.x;
    const int wv   = tid >> 6;
    const int lane = tid & 63;
    const int g = lane >> 4, c = lane & 15;

    s16x8 qa[4];
    #pragma unroll
    for (int ms = 0; ms < 4; ++ms)
        qa[ms] = *(const s16x8*)(qt + ((size_t)bh*NN + m0 + ms*16 + c)*HDP + g*8);

    const f32x4 zero4 = {0.f, 0.f, 0.f, 0.f};
    f32x4 z[4];
    #pragma unroll
    for (int ms = 0; ms < 4; ++ms) z[ms] = zero4;

    const unsigned short* kbase = kt + (size_t)bh*NN*HDP;
    const int nbeg = wv * (NN/4);
    const int nend = nbeg + NN/4;

    s16x8 kb0 = *(const s16x8*)(kbase + (size_t)(nbeg +      c)*HDP + g*8);
    s16x8 kb1 = *(const s16x8*)(kbase + (size_t)(nbeg + 16 + c)*HDP + g*8);

    for (int n = nbeg; n < nend - 32; n += 32) {
        s16x8 nk0 = *(const s16x8*)(kbase + (size_t)(n + 32 +      c)*HDP + g*8);
        s16x8 nk1 = *(const s16x8*)(kbase + (size_t)(n + 48 +      c)*HDP + g*8);
        #pragma unroll
        for (int ms = 0; ms < 4; ++ms) {
            f32x4 e0 = mfma32(qa[ms], kb0, zero4);
            f32x4 e1 = mfma32(qa[ms], kb1, zero4);
            #pragma unroll
            for (int rr = 0; rr < 4; ++rr)
                z[ms][rr] += exp2fast(e0[rr]) + exp2fast(e1[rr]);
        }
        kb0 = nk0; kb1 = nk1;
    }
    #pragma unroll
    for (int ms = 0; ms < 4; ++ms) {
        f32x4 e0 = mfma32(qa[ms], kb0, zero4);
        f32x4 e1 = mfma32(qa[ms], kb1, zero4);
        #pragma unroll
        for (int rr = 0; rr < 4; ++rr)
            z[ms][rr] += exp2fast(e0[rr]) + exp2fast(e1[rr]);
    }

    #pragma unroll
    for (int ms = 0; ms < 4; ++ms) {
        #pragma unroll
        for (int rr = 0; rr < 4; ++rr) {
            float v = z[ms][rr];
            v += __shfl_xor(v, 1);
            v += __shfl_xor(v, 2);
            v += __shfl_xor(v, 4);
            v += __shfl_xor(v, 8);
            if (c == 0) zred[wv][ms*16 + g*4 + rr] = v;
        }
    }
    __syncthreads();
    if (tid < 64) {
        float s = zred[0][tid] + zred[1][tid] + zred[2][tid] + zred[3][tid];
        zinv[(size_t)bh*NN + m0 + tid] = 1.0f / s;
    }
}

// ---------------- vzb[bh][dp][m] = bf16(v[dp][m] * zinv[m]), pad rows 0 --
__global__ __launch_bounds__(256)
void vz_kernel(const unsigned short* __restrict__ vb,
               const float* __restrict__ zinv,
               unsigned short* __restrict__ vzb)
{
    size_t idx = (size_t)blockIdx.x*256 + threadIdx.x;   // over NBH*HDP*NN
    int m  = (int)(idx % NN);
    int t  = (int)(idx / NN);
    int dp = t % HDP;
    int bh = t / HDP;
    float val = 0.f;
    if (dp < HD)
        val = bf2f(vb[((size_t)bh*HD + dp)*NN + m]) * zinv[(size_t)bh*NN + m];
    vzb[idx] = f2bf(val);
}

// ---------------- Pass 2: out = Vz * exp2(Q^T K) ------------------------
// R14: 1-step-deep P software pipeline (T15 mechanism). Iteration k:
//   (1) issue loads frags(k+1)   -> consumed next iter
//   (2) compute P(k) from qa(k)  -> qa loaded previous iter
//   (3) PV: acc += va(k-1) (x) P(k-1)  -> operands all ready, no waits
// Nothing in an iteration depends on anything produced in that iteration.
// Block = 64 n-cols (kb[4] invariant), 4 waves split m, LDS reduce, swizzle.
__global__ __launch_bounds__(256, 3)
void attn_out_kernel(const unsigned short* __restrict__ qt,
                     const unsigned short* __restrict__ kt,
                     const unsigned short* __restrict__ vzb,
                     float* __restrict__ y)
{
    __shared__ float red[3][32][64];   // 24 KB
    const int blk  = ((int)blockIdx.x & 7) * (NBH*(NN/64)/8) + ((int)blockIdx.x >> 3);
    const int bh   = blk / (NN/64);
    const int n0   = (blk % (NN/64)) * 64;
    const int tid  = threadIdx.x;
    const int wv   = tid >> 6;
    const int lane = tid & 63;
    const int g = lane >> 4, c = lane & 15;
    const int b = bh >> 3, nh = bh & 7;

    const f32x4 zero4 = {0.f, 0.f, 0.f, 0.f};
    const unsigned short* qb  = qt  + (size_t)bh*NN*HDP;
    const unsigned short* kbp = kt  + (size_t)bh*NN*HDP;
    const unsigned short* vp  = vzb + (size_t)bh*HDP*NN;

    s16x8 kb[4];
    #pragma unroll
    for (int ns = 0; ns < 4; ++ns)
        kb[ns] = *(const s16x8*)(kbp + ((size_t)(n0 + ns*16 + c))*HDP + g*8);

    f32x4 acc[2][4];
    #pragma unroll
    for (int ds = 0; ds < 2; ++ds)
        #pragma unroll
        for (int ns = 0; ns < 4; ++ns) acc[ds][ns] = zero4;

    const int mbeg = wv * (NN/4);          // 960 m per wave = 30 steps of 32

    // ---- prologue ----
    // frags(0)
    s16x8 qa0 = *(const s16x8*)(qb + (size_t)(mbeg +      c)*HDP + g*8);
    s16x8 qa1 = *(const s16x8*)(qb + (size_t)(mbeg + 16 + c)*HDP + g*8);
    s16x4 vaPV00 = *(const s16x4*)(vp + (size_t)(     c)*NN + mbeg +      g*4);
    s16x4 vaPV01 = *(const s16x4*)(vp + (size_t)(     c)*NN + mbeg + 16 + g*4);
    s16x4 vaPV10 = *(const s16x4*)(vp + (size_t)(16 + c)*NN + mbeg +      g*4);
    s16x4 vaPV11 = *(const s16x4*)(vp + (size_t)(16 + c)*NN + mbeg + 16 + g*4);
    // frags(1) in flight
    s16x8 nqa0 = *(const s16x8*)(qb + (size_t)(mbeg + 32 +      c)*HDP + g*8);
    s16x8 nqa1 = *(const s16x8*)(qb + (size_t)(mbeg + 32 + 16 + c)*HDP + g*8);
    s16x4 nva00 = *(const s16x4*)(vp + (size_t)(     c)*NN + mbeg + 32 +      g*4);
    s16x4 nva01 = *(const s16x4*)(vp + (size_t)(     c)*NN + mbeg + 32 + 16 + g*4);
    s16x4 nva10 = *(const s16x4*)(vp + (size_t)(16 + c)*NN + mbeg + 32 +      g*4);
    s16x4 nva11 = *(const s16x4*)(vp + (size_t)(16 + c)*NN + mbeg + 32 + 16 + g*4);
    // P(0) from frags(0)
    s16x4 p0[4], p1[4];
    #pragma unroll
    for (int ns = 0; ns < 4; ++ns) {
        f32x4 e0 = mfma32(qa0, kb[ns], zero4);
        f32x4 e1 = mfma32(qa1, kb[ns], zero4);
        p0[ns] = exp4_pack(e0);
        p1[ns] = exp4_pack(e1);
    }

    // ---- main loop: k = 1 .. 28 ----
    for (int k = 1; k <= 28; ++k) {
        const int m2 = mbeg + (k+1)*32;
        // (1) issue loads frags(k+1)
        s16x8 nnqa0 = *(const s16x8*)(qb + (size_t)(m2 +      c)*HDP + g*8);
        s16x8 nnqa1 = *(const s16x8*)(qb + (size_t)(m2 + 16 + c)*HDP + g*8);
        s16x4 nnva00 = *(const s16x4*)(vp + (size_t)(     c)*NN + m2 +      g*4);
        s16x4 nnva01 = *(const s16x4*)(vp + (size_t)(     c)*NN + m2 + 16 + g*4);
        s16x4 nnva10 = *(const s16x4*)(vp + (size_t)(16 + c)*NN + m2 +      g*4);
        s16x4 nnva11 = *(const s16x4*)(vp + (size_t)(16 + c)*NN + m2 + 16 + g*4);
        // (2) compute P(k) from frags(k) [loaded previous iter]
        s16x4 np0[4], np1[4];
        #pragma unroll
        for (int ns = 0; ns < 4; ++ns) {
            f32x4 e0 = mfma32(nqa0, kb[ns], zero4);
            f32x4 e1 = mfma32(nqa1, kb[ns], zero4);
            np0[ns] = exp4_pack(e0);
            np1[ns] = exp4_pack(e1);
        }
        // (3) PV step k-1: all operands ready since last iteration
        #pragma unroll
        for (int ns = 0; ns < 4; ++ns) {
            acc[0][ns] = mfma16(vaPV00, p0[ns], acc[0][ns]);
            acc[0][ns] = mfma16(vaPV01, p1[ns], acc[0][ns]);
            acc[1][ns] = mfma16(vaPV10, p0[ns], acc[1][ns]);
            acc[1][ns] = mfma16(vaPV11, p1[ns], acc[1][ns]);
        }
        // rotate
        #pragma unroll
        for (int ns = 0; ns < 4; ++ns) { p0[ns] = np0[ns]; p1[ns] = np1[ns]; }
        vaPV00 = nva00; vaPV01 = nva01; vaPV10 = nva10; vaPV11 = nva11;
        nqa0 = nnqa0; nqa1 = nnqa1;
        nva00 = nnva00; nva01 = nnva01; nva10 = nnva10; nva11 = nnva11;
    }

    // ---- epilogue ----
    {   // P(29) from frags(29)
        s16x4 np0[4], np1[4];
        #pragma unroll
        for (int ns = 0; ns < 4; ++ns) {
            f32x4 e0 = mfma32(nqa0, kb[ns], zero4);
            f32x4 e1 = mfma32(nqa1, kb[ns], zero4);
            np0[ns] = exp4_pack(e0);
            np1[ns] = exp4_pack(e1);
        }
        // PV step 28
        #pragma unroll
        for (int ns = 0; ns < 4; ++ns) {
            acc[0][ns] = mfma16(vaPV00, p0[ns], acc[0][ns]);
            acc[0][ns] = mfma16(vaPV01, p1[ns], acc[0][ns]);
            acc[1][ns] = mfma16(vaPV10, p0[ns], acc[1][ns]);
            acc[1][ns] = mfma16(vaPV11, p1[ns], acc[1][ns]);
        }
        // PV step 29
        #pragma unroll
        for (int ns = 0; ns < 4; ++ns) {
            acc[0][ns] = mfma16(nva00, np0[ns], acc[0][ns]);
            acc[0][ns] = mfma16(nva01, np1[ns], acc[0][ns]);
            acc[1][ns] = mfma16(nva10, np0[ns], acc[1][ns]);
            acc[1][ns] = mfma16(nva11, np1[ns], acc[1][ns]);
        }
    }

    float* af = (float*)acc;   // 32 contiguous f32
    if (wv > 0) {
        #pragma unroll
        for (int j = 0; j < 32; ++j) red[wv-1][j][lane] = af[j];
    }
    __syncthreads();
    if (wv == 0) {
        #pragma unroll
        for (int j = 0; j < 32; ++j)
            af[j] += red[0][j][lane] + red[1][j][lane] + red[2][j][lane];
        float* yb = y + (size_t)b * CC * HH * WW;
        #pragma unroll
        for (int ds = 0; ds < 2; ++ds) {
            #pragma unroll
            for (int ns = 0; ns < 4; ++ns) {
                #pragma unroll
                for (int rr = 0; rr < 4; ++rr) {
                    int dd = ds*16 + g*4 + rr;
                    if (dd < HD)
                        yb[((size_t)(dd*NH_ + nh))*NN + n0 + ns*16 + c] = acc[ds][ns][rr];
                }
            }
        }
    }
}

extern "C" void kernel_launch(void* const* d_in, const int* in_sizes, int n_in,
                              void* d_out, int out_size, void* d_ws, size_t ws_size,
                              hipStream_t stream)
{
    const float* x  = (const float*)d_in[0];
    const float* Wq = (const float*)d_in[1];
    const float* bq = (const float*)d_in[2];
    const float* Wk = (const float*)d_in[3];
    const float* bk = (const float*)d_in[4];
    const float* Wv = (const float*)d_in[5];
    const float* bv = (const float*)d_in[6];
    float* y = (float*)d_out;

    const size_t QT_E = (size_t)NBH * NN * HDP;      // 3,932,160 bf16
    unsigned short* qt  = (unsigned short*)d_ws;
    unsigned short* kt  = qt + QT_E;
    unsigned short* vb  = kt + QT_E;
    unsigned short* vzb = vb + (size_t)NBH * HD * NN;
    float*          zinv = (float*)(vzb + QT_E);
    unsigned short* wqb = (unsigned short*)(zinv + (size_t)NBH*NN);
    unsigned short* wkb = wqb + WW*WW;
    unsigned short* wvb = wkb + WW*WW;               // total ~29.2 MB

    hipMemsetAsync(qt, 0, 2 * QT_E * sizeof(unsigned short), stream);

    wprep_kernel<<<dim3((WW*WW + 255)/256), dim3(256), 0, stream>>>(
        Wq, Wk, Wv, wqb, wkb, wvb);
    proj_mfma_kernel<<<dim3(BB*ROWS/64), dim3(256), 0, stream>>>(
        x, wqb, wkb, wvb, bq, bk, bv, qt, kt, vb);
    zinv_kernel<<<dim3(NBH*(NN/64)), dim3(256), 0, stream>>>(qt, kt, zinv);
    vz_kernel<<<dim3((NBH*HDP*NN)/256), dim3(256), 0, stream>>>(vb, zinv, vzb);
    attn_out_kernel<<<dim3(NBH*(NN/64)), dim3(256), 0, stream>>>(qt, kt, vzb, y);
}

// Round 15
// 252.725 us; speedup vs baseline: 1.4405x; 1.0006x over previous
//
#include <hip/hip_runtime.h>
#include <hip/hip_bf16.h>
#include <math.h>

#define BB   4
#define CC   32
#define HH   120
#define WW   160
#define NH_  8
#define HD   20
#define HDP  32            // head dim padded to 32 (zeros) for K=32 MFMA
#define NN   3840          // sequence length (C*H)
#define ROWS 3840
#define NBH  32            // B * NH
#define LOG2E 1.44269504088896f

typedef float f32x4 __attribute__((ext_vector_type(4)));
typedef short s16x8 __attribute__((ext_vector_type(8)));
typedef short s16x4 __attribute__((ext_vector_type(4)));

static __device__ __forceinline__ unsigned short f2bf(float x) {
    return __builtin_bit_cast(unsigned short, __float2bfloat16(x));
}
static __device__ __forceinline__ float bf2f(unsigned short u) {
    unsigned v = ((unsigned)u) << 16;
    return __builtin_bit_cast(float, v);
}
static __device__ __forceinline__ float exp2fast(float x) {
#if defined(__has_builtin) && __has_builtin(__builtin_amdgcn_exp2f)
    return __builtin_amdgcn_exp2f(x);
#else
    float r; asm("v_exp_f32 %0, %1" : "=v"(r) : "v"(x)); return r;
#endif
}

// exp2 four lanes then pack to bf16 (round-half-up) as an s16x4 B-frag.
// BUILTIN-ONLY pack — validated R5/R9-R14. Do NOT use the cvt_pk inline-asm
// variant (R7/R8 corruption in unrolled loops).
static __device__ __forceinline__ s16x4 exp4_pack(f32x4 e) {
    unsigned u0 = __builtin_bit_cast(unsigned, exp2fast(e[0])) + 0x8000u;
    unsigned u1 = __builtin_bit_cast(unsigned, exp2fast(e[1])) + 0x8000u;
    unsigned u2 = __builtin_bit_cast(unsigned, exp2fast(e[2])) + 0x8000u;
    unsigned u3 = __builtin_bit_cast(unsigned, exp2fast(e[3])) + 0x8000u;
    uint2 w;
#if defined(__has_builtin) && __has_builtin(__builtin_amdgcn_perm)
    w.x = __builtin_amdgcn_perm(u1, u0, 0x07060302u);
    w.y = __builtin_amdgcn_perm(u3, u2, 0x07060302u);
#else
    w.x = (u0 >> 16) | (u1 & 0xffff0000u);
    w.y = (u2 >> 16) | (u3 & 0xffff0000u);
#endif
    return __builtin_bit_cast(s16x4, w);
}

static __device__ __forceinline__ f32x4 mfma32(s16x8 a, s16x8 b, f32x4 c) {
    return __builtin_amdgcn_mfma_f32_16x16x32_bf16(a, b, c, 0, 0, 0);
}
// concat two s16x4 into a K=32 fragment half-pair (register pairing, no ops)
static __device__ __forceinline__ s16x8 cat44(s16x4 a, s16x4 b) {
    s16x8 r;
    r[0]=a[0]; r[1]=a[1]; r[2]=a[2]; r[3]=a[3];
    r[4]=b[0]; r[5]=b[1]; r[6]=b[2]; r[7]=b[3];
    return r;
}

// ---------------- W prep: f32 -> bf16 [o][k]; Wq pre-scaled by log2(e) ----
__global__ __launch_bounds__(256)
void wprep_kernel(const float* __restrict__ Wq, const float* __restrict__ Wk,
                  const float* __restrict__ Wv,
                  unsigned short* __restrict__ wqb, unsigned short* __restrict__ wkb,
                  unsigned short* __restrict__ wvb)
{
    int i = blockIdx.x*256 + threadIdx.x;
    if (i < WW*WW) {
        wqb[i] = f2bf(Wq[i] * LOG2E);
        wkb[i] = f2bf(Wk[i]);
        wvb[i] = f2bf(Wv[i]);
    }
}

// ---------------- Projection via MFMA (no LDS) ---------------------------
__global__ __launch_bounds__(256)
void proj_mfma_kernel(const float* __restrict__ x,
                      const unsigned short* __restrict__ wqb,
                      const unsigned short* __restrict__ wkb,
                      const unsigned short* __restrict__ wvb,
                      const float* __restrict__ bq, const float* __restrict__ bk,
                      const float* __restrict__ bv,
                      unsigned short* __restrict__ qt, unsigned short* __restrict__ kt,
                      unsigned short* __restrict__ vb)
{
    const int tid  = threadIdx.x;
    const int wv   = tid >> 6;
    const int lane = tid & 63;
    const int g = lane >> 4, c = lane & 15;
    const int r0 = blockIdx.x*64 + wv*16;

    s16x8 A[5];
    const float* xrow = x + (size_t)(r0 + c)*WW;
    #pragma unroll
    for (int s = 0; s < 5; ++s) {
        float4 v0 = *(const float4*)(xrow + s*32 + g*8);
        float4 v1 = *(const float4*)(xrow + s*32 + g*8 + 4);
        s16x8 a;
        a[0]=(short)f2bf(v0.x); a[1]=(short)f2bf(v0.y);
        a[2]=(short)f2bf(v0.z); a[3]=(short)f2bf(v0.w);
        a[4]=(short)f2bf(v1.x); a[5]=(short)f2bf(v1.y);
        a[6]=(short)f2bf(v1.z); a[7]=(short)f2bf(v1.w);
        A[s] = a;
    }

    size_t baseqk[4], basev[4];
    #pragma unroll
    for (int rr = 0; rr < 4; ++rr) {
        int R  = r0 + g*4 + rr;
        int b  = R / ROWS;
        int r  = R % ROWS;
        int nh = r / 480;
        int rm = r % 480;
        int d  = rm / 24;
        int n1 = rm % 24;
        int bh = b*NH_ + nh;
        baseqk[rr] = ((size_t)bh*NN + n1*160)*HDP + d;
        basev[rr]  = ((size_t)bh*HD + d)*NN + n1*160;
    }

    const f32x4 zero4 = {0.f, 0.f, 0.f, 0.f};
    for (int nt = 0; nt < 10; ++nt) {
        const size_t wbase = (size_t)(nt*16 + c)*WW;
        f32x4 aq = zero4, ak = zero4, av = zero4;
        #pragma unroll
        for (int s = 0; s < 5; ++s) {
            s16x8 Bq = *(const s16x8*)(wqb + wbase + s*32 + g*8);
            aq = mfma32(A[s], Bq, aq);
            s16x8 Bk = *(const s16x8*)(wkb + wbase + s*32 + g*8);
            ak = mfma32(A[s], Bk, ak);
            s16x8 Bv = *(const s16x8*)(wvb + wbase + s*32 + g*8);
            av = mfma32(A[s], Bv, av);
        }
        const int o = nt*16 + c;
        const float bqv = bq[o]*LOG2E, bkv = bk[o], bvv = bv[o];
        #pragma unroll
        for (int rr = 0; rr < 4; ++rr) {
            qt[baseqk[rr] + (size_t)o*HDP] = f2bf(aq[rr] + bqv);
            kt[baseqk[rr] + (size_t)o*HDP] = f2bf(ak[rr] + bkv);
            vb[basev[rr] + o]              = f2bf(av[rr] + bvv);
        }
    }
}

// ---------------- Pass 1: zinv[m] = 1 / sum_n exp2(E[m,n]) ---------------
// R12-exact (passing): 1920 blocks, XCD swizzle, 1-deep K prefetch.
__global__ __launch_bounds__(256, 4)
void zinv_kernel(const unsigned short* __restrict__ qt,
                 const unsigned short* __restrict__ kt,
                 float* __restrict__ zinv)
{
    __shared__ float zred[4][64];
    const int blk  = ((int)blockIdx.x & 7) * (NBH*(NN/64)/8) + ((int)blockIdx.x >> 3);
    const int bh   = blk / (NN/64);
    const int m0   = (blk % (NN/64)) * 64;
    const int tid  = threadIdx.x;
    const int wv   = tid >> 6;
    const int lane = tid & 63;
    const int g = lane >> 4, c = lane & 15;

    s16x8 qa[4];
    #pragma unroll
    for (int ms = 0; ms < 4; ++ms)
        qa[ms] = *(const s16x8*)(qt + ((size_t)bh*NN + m0 + ms*16 + c)*HDP + g*8);

    const f32x4 zero4 = {0.f, 0.f, 0.f, 0.f};
    f32x4 z[4];
    #pragma unroll
    for (int ms = 0; ms < 4; ++ms) z[ms] = zero4;

    const unsigned short* kbase = kt + (size_t)bh*NN*HDP;
    const int nbeg = wv * (NN/4);
    const int nend = nbeg + NN/4;

    s16x8 kb0 = *(const s16x8*)(kbase + (size_t)(nbeg +      c)*HDP + g*8);
    s16x8 kb1 = *(const s16x8*)(kbase + (size_t)(nbeg + 16 + c)*HDP + g*8);

    for (int n = nbeg; n < nend - 32; n += 32) {
        s16x8 nk0 = *(const s16x8*)(kbase + (size_t)(n + 32 +      c)*HDP + g*8);
        s16x8 nk1 = *(const s16x8*)(kbase + (size_t)(n + 48 +      c)*HDP + g*8);
        #pragma unroll
        for (int ms = 0; ms < 4; ++ms) {
            f32x4 e0 = mfma32(qa[ms], kb0, zero4);
            f32x4 e1 = mfma32(qa[ms], kb1, zero4);
            #pragma unroll
            for (int rr = 0; rr < 4; ++rr)
                z[ms][rr] += exp2fast(e0[rr]) + exp2fast(e1[rr]);
        }
        kb0 = nk0; kb1 = nk1;
    }
    #pragma unroll
    for (int ms = 0; ms < 4; ++ms) {
        f32x4 e0 = mfma32(qa[ms], kb0, zero4);
        f32x4 e1 = mfma32(qa[ms], kb1, zero4);
        #pragma unroll
        for (int rr = 0; rr < 4; ++rr)
            z[ms][rr] += exp2fast(e0[rr]) + exp2fast(e1[rr]);
    }

    #pragma unroll
    for (int ms = 0; ms < 4; ++ms) {
        #pragma unroll
        for (int rr = 0; rr < 4; ++rr) {
            float v = z[ms][rr];
            v += __shfl_xor(v, 1);
            v += __shfl_xor(v, 2);
            v += __shfl_xor(v, 4);
            v += __shfl_xor(v, 8);
            if (c == 0) zred[wv][ms*16 + g*4 + rr] = v;
        }
    }
    __syncthreads();
    if (tid < 64) {
        float s = zred[0][tid] + zred[1][tid] + zred[2][tid] + zred[3][tid];
        zinv[(size_t)bh*NN + m0 + tid] = 1.0f / s;
    }
}

// ---------------- vzb[bh][dp][m] = bf16(v[dp][m] * zinv[m]), pad rows 0 --
__global__ __launch_bounds__(256)
void vz_kernel(const unsigned short* __restrict__ vb,
               const float* __restrict__ zinv,
               unsigned short* __restrict__ vzb)
{
    size_t idx = (size_t)blockIdx.x*256 + threadIdx.x;   // over NBH*HDP*NN
    int m  = (int)(idx % NN);
    int t  = (int)(idx / NN);
    int dp = t % HDP;
    int bh = t / HDP;
    float val = 0.f;
    if (dp < HD)
        val = bf2f(vb[((size_t)bh*HD + dp)*NN + m]) * zinv[(size_t)bh*NN + m];
    vzb[idx] = f2bf(val);
}

// ---------------- Pass 2: out = Vz * exp2(Q^T K) ------------------------
// R15 delta on R12 base: PV via K=32 mfma32 with the pi-permutation trick
// (NO mfma16, NO inline asm in the loop). PV = sum_m Vz[d][m]*P[m][n] is
// invariant under a shared K-permutation: P's natural D-frag order at lane
// (g,c) is pi(g,j) = (j<4 ? 4g+j : 16+4g+j-4); cat44(va[ds][0],va[ds][1])
// supplies Vz in exactly the same pi order. D-frag layout of the 16x16
// family is K-independent, so acc layout and C-write are unchanged.
__global__ __launch_bounds__(256, 3)
void attn_out_kernel(const unsigned short* __restrict__ qt,
                     const unsigned short* __restrict__ kt,
                     const unsigned short* __restrict__ vzb,
                     float* __restrict__ y)
{
    __shared__ float red[3][32][64];   // 24 KB
    const int blk  = ((int)blockIdx.x & 7) * (NBH*(NN/64)/8) + ((int)blockIdx.x >> 3);
    const int bh   = blk / (NN/64);
    const int n0   = (blk % (NN/64)) * 64;
    const int tid  = threadIdx.x;
    const int wv   = tid >> 6;
    const int lane = tid & 63;
    const int g = lane >> 4, c = lane & 15;
    const int b = bh >> 3, nh = bh & 7;

    const f32x4 zero4 = {0.f, 0.f, 0.f, 0.f};
    const unsigned short* qb  = qt  + (size_t)bh*NN*HDP;
    const unsigned short* kbp = kt  + (size_t)bh*NN*HDP;
    const unsigned short* vp  = vzb + (size_t)bh*HDP*NN;

    s16x8 kb[4];
    #pragma unroll
    for (int ns = 0; ns < 4; ++ns)
        kb[ns] = *(const s16x8*)(kbp + ((size_t)(n0 + ns*16 + c))*HDP + g*8);

    f32x4 acc[2][4];
    #pragma unroll
    for (int ds = 0; ds < 2; ++ds)
        #pragma unroll
        for (int ns = 0; ns < 4; ++ns) acc[ds][ns] = zero4;

    const int mbeg = wv * (NN/4);          // 960 m per wave = 15 steps of 64
    const int mend = mbeg + NN/4;

    // current-step fragments (64 m)
    s16x8 qa[4];
    s16x4 va[2][4];
    #pragma unroll
    for (int j = 0; j < 4; ++j)
        qa[j] = *(const s16x8*)(qb + ((size_t)(mbeg + j*16 + c))*HDP + g*8);
    #pragma unroll
    for (int ds = 0; ds < 2; ++ds)
        #pragma unroll
        for (int j = 0; j < 4; ++j)
            va[ds][j] = *(const s16x4*)(vp + ((size_t)(ds*16 + c))*NN
                                           + mbeg + j*16 + g*4);

    for (int m0 = mbeg; m0 < mend - 64; m0 += 64) {
        const int m1 = m0 + 64;
        // prefetch next step
        s16x8 nqa[4];
        s16x4 nva[2][4];
        #pragma unroll
        for (int j = 0; j < 4; ++j)
            nqa[j] = *(const s16x8*)(qb + ((size_t)(m1 + j*16 + c))*HDP + g*8);
        #pragma unroll
        for (int ds = 0; ds < 2; ++ds)
            #pragma unroll
            for (int j = 0; j < 4; ++j)
                nva[ds][j] = *(const s16x4*)(vp + ((size_t)(ds*16 + c))*NN
                                                + m1 + j*16 + g*4);

        #pragma unroll
        for (int ns = 0; ns < 4; ++ns) {
            f32x4 e0 = mfma32(qa[0], kb[ns], zero4);
            f32x4 e1 = mfma32(qa[1], kb[ns], zero4);
            f32x4 e2 = mfma32(qa[2], kb[ns], zero4);
            f32x4 e3 = mfma32(qa[3], kb[ns], zero4);
            s16x8 P01 = cat44(exp4_pack(e0), exp4_pack(e1));   // m0..m0+31  (pi order)
            s16x8 P23 = cat44(exp4_pack(e2), exp4_pack(e3));   // m0+32..+63 (pi order)
            acc[0][ns] = mfma32(cat44(va[0][0], va[0][1]), P01, acc[0][ns]);
            acc[0][ns] = mfma32(cat44(va[0][2], va[0][3]), P23, acc[0][ns]);
            acc[1][ns] = mfma32(cat44(va[1][0], va[1][1]), P01, acc[1][ns]);
            acc[1][ns] = mfma32(cat44(va[1][2], va[1][3]), P23, acc[1][ns]);
        }
        #pragma unroll
        for (int j = 0; j < 4; ++j) qa[j] = nqa[j];
        #pragma unroll
        for (int ds = 0; ds < 2; ++ds)
            #pragma unroll
            for (int j = 0; j < 4; ++j) va[ds][j] = nva[ds][j];
    }
    // epilogue: last 64-m step
    #pragma unroll
    for (int ns = 0; ns < 4; ++ns) {
        f32x4 e0 = mfma32(qa[0], kb[ns], zero4);
        f32x4 e1 = mfma32(qa[1], kb[ns], zero4);
        f32x4 e2 = mfma32(qa[2], kb[ns], zero4);
        f32x4 e3 = mfma32(qa[3], kb[ns], zero4);
        s16x8 P01 = cat44(exp4_pack(e0), exp4_pack(e1));
        s16x8 P23 = cat44(exp4_pack(e2), exp4_pack(e3));
        acc[0][ns] = mfma32(cat44(va[0][0], va[0][1]), P01, acc[0][ns]);
        acc[0][ns] = mfma32(cat44(va[0][2], va[0][3]), P23, acc[0][ns]);
        acc[1][ns] = mfma32(cat44(va[1][0], va[1][1]), P01, acc[1][ns]);
        acc[1][ns] = mfma32(cat44(va[1][2], va[1][3]), P23, acc[1][ns]);
    }

    float* af = (float*)acc;   // 32 contiguous f32
    if (wv > 0) {
        #pragma unroll
        for (int j = 0; j < 32; ++j) red[wv-1][j][lane] = af[j];
    }
    __syncthreads();
    if (wv == 0) {
        #pragma unroll
        for (int j = 0; j < 32; ++j)
            af[j] += red[0][j][lane] + red[1][j][lane] + red[2][j][lane];
        float* yb = y + (size_t)b * CC * HH * WW;
        #pragma unroll
        for (int ds = 0; ds < 2; ++ds) {
            #pragma unroll
            for (int ns = 0; ns < 4; ++ns) {
                #pragma unroll
                for (int rr = 0; rr < 4; ++rr) {
                    int dd = ds*16 + g*4 + rr;
                    if (dd < HD)
                        yb[((size_t)(dd*NH_ + nh))*NN + n0 + ns*16 + c] = acc[ds][ns][rr];
                }
            }
        }
    }
}

extern "C" void kernel_launch(void* const* d_in, const int* in_sizes, int n_in,
                              void* d_out, int out_size, void* d_ws, size_t ws_size,
                              hipStream_t stream)
{
    const float* x  = (const float*)d_in[0];
    const float* Wq = (const float*)d_in[1];
    const float* bq = (const float*)d_in[2];
    const float* Wk = (const float*)d_in[3];
    const float* bk = (const float*)d_in[4];
    const float* Wv = (const float*)d_in[5];
    const float* bv = (const float*)d_in[6];
    float* y = (float*)d_out;

    const size_t QT_E = (size_t)NBH * NN * HDP;      // 3,932,160 bf16
    unsigned short* qt  = (unsigned short*)d_ws;
    unsigned short* kt  = qt + QT_E;
    unsigned short* vb  = kt + QT_E;
    unsigned short* vzb = vb + (size_t)NBH * HD * NN;
    float*          zinv = (float*)(vzb + QT_E);
    unsigned short* wqb = (unsigned short*)(zinv + (size_t)NBH*NN);
    unsigned short* wkb = wqb + WW*WW;
    unsigned short* wvb = wkb + WW*WW;               // total ~29.2 MB

    hipMemsetAsync(qt, 0, 2 * QT_E * sizeof(unsigned short), stream);

    wprep_kernel<<<dim3((WW*WW + 255)/256), dim3(256), 0, stream>>>(
        Wq, Wk, Wv, wqb, wkb, wvb);
    proj_mfma_kernel<<<dim3(BB*ROWS/64), dim3(256), 0, stream>>>(
        x, wqb, wkb, wvb, bq, bk, bv, qt, kt, vb);
    zinv_kernel<<<dim3(NBH*(NN/64)), dim3(256), 0, stream>>>(qt, kt, zinv);
    vz_kernel<<<dim3((NBH*HDP*NN)/256), dim3(256), 0, stream>>>(vb, zinv, vzb);
    attn_out_kernel<<<dim3(NBH*(NN/64)), dim3(256), 0, stream>>>(qt, kt, vzb, y);
}

// Round 16
// 190.066 us; speedup vs baseline: 1.9154x; 1.3297x over previous
//
#include <hip/hip_runtime.h>
#include <hip/hip_bf16.h>
#include <math.h>

#define BB   4
#define CC   32
#define HH   120
#define WW   160
#define NH_  8
#define HD   20
#define HDP  32            // head dim padded to 32 (zeros) for K=32 MFMA
#define NN   3840          // sequence length (C*H)
#define ROWS 3840
#define NBH  32            // B * NH
#define LOG2E 1.44269504088896f

typedef float f32x4 __attribute__((ext_vector_type(4)));
typedef short s16x8 __attribute__((ext_vector_type(8)));
typedef short s16x4 __attribute__((ext_vector_type(4)));

static __device__ __forceinline__ unsigned short f2bf(float x) {
    return __builtin_bit_cast(unsigned short, __float2bfloat16(x));
}
static __device__ __forceinline__ float bf2f(unsigned short u) {
    unsigned v = ((unsigned)u) << 16;
    return __builtin_bit_cast(float, v);
}
static __device__ __forceinline__ float exp2fast(float x) {
#if defined(__has_builtin) && __has_builtin(__builtin_amdgcn_exp2f)
    return __builtin_amdgcn_exp2f(x);
#else
    float r; asm("v_exp_f32 %0, %1" : "=v"(r) : "v"(x)); return r;
#endif
}

// exp2 four lanes then pack to bf16 (round-half-up) as an s16x4 B-frag.
// BUILTIN-ONLY pack — validated R5/R9-R15. Do NOT use the cvt_pk inline-asm
// variant (R7/R8 corruption in unrolled loops).
static __device__ __forceinline__ s16x4 exp4_pack(f32x4 e) {
    unsigned u0 = __builtin_bit_cast(unsigned, exp2fast(e[0])) + 0x8000u;
    unsigned u1 = __builtin_bit_cast(unsigned, exp2fast(e[1])) + 0x8000u;
    unsigned u2 = __builtin_bit_cast(unsigned, exp2fast(e[2])) + 0x8000u;
    unsigned u3 = __builtin_bit_cast(unsigned, exp2fast(e[3])) + 0x8000u;
    uint2 w;
#if defined(__has_builtin) && __has_builtin(__builtin_amdgcn_perm)
    w.x = __builtin_amdgcn_perm(u1, u0, 0x07060302u);
    w.y = __builtin_amdgcn_perm(u3, u2, 0x07060302u);
#else
    w.x = (u0 >> 16) | (u1 & 0xffff0000u);
    w.y = (u2 >> 16) | (u3 & 0xffff0000u);
#endif
    return __builtin_bit_cast(s16x4, w);
}

static __device__ __forceinline__ f32x4 mfma32(s16x8 a, s16x8 b, f32x4 c) {
    return __builtin_amdgcn_mfma_f32_16x16x32_bf16(a, b, c, 0, 0, 0);
}
// concat two s16x4 into a K=32 fragment half-pair (register pairing, no ops)
static __device__ __forceinline__ s16x8 cat44(s16x4 a, s16x4 b) {
    s16x8 r;
    r[0]=a[0]; r[1]=a[1]; r[2]=a[2]; r[3]=a[3];
    r[4]=b[0]; r[5]=b[1]; r[6]=b[2]; r[7]=b[3];
    return r;
}

// ---------------- W prep: f32 -> bf16 [o][k]; Wq pre-scaled by log2(e) ----
__global__ __launch_bounds__(256)
void wprep_kernel(const float* __restrict__ Wq, const float* __restrict__ Wk,
                  const float* __restrict__ Wv,
                  unsigned short* __restrict__ wqb, unsigned short* __restrict__ wkb,
                  unsigned short* __restrict__ wvb)
{
    int i = blockIdx.x*256 + threadIdx.x;
    if (i < WW*WW) {
        wqb[i] = f2bf(Wq[i] * LOG2E);
        wkb[i] = f2bf(Wk[i]);
        wvb[i] = f2bf(Wv[i]);
    }
}

// ---------------- Projection via MFMA (no LDS) ---------------------------
__global__ __launch_bounds__(256)
void proj_mfma_kernel(const float* __restrict__ x,
                      const unsigned short* __restrict__ wqb,
                      const unsigned short* __restrict__ wkb,
                      const unsigned short* __restrict__ wvb,
                      const float* __restrict__ bq, const float* __restrict__ bk,
                      const float* __restrict__ bv,
                      unsigned short* __restrict__ qt, unsigned short* __restrict__ kt,
                      unsigned short* __restrict__ vb)
{
    const int tid  = threadIdx.x;
    const int wv   = tid >> 6;
    const int lane = tid & 63;
    const int g = lane >> 4, c = lane & 15;
    const int r0 = blockIdx.x*64 + wv*16;

    s16x8 A[5];
    const float* xrow = x + (size_t)(r0 + c)*WW;
    #pragma unroll
    for (int s = 0; s < 5; ++s) {
        float4 v0 = *(const float4*)(xrow + s*32 + g*8);
        float4 v1 = *(const float4*)(xrow + s*32 + g*8 + 4);
        s16x8 a;
        a[0]=(short)f2bf(v0.x); a[1]=(short)f2bf(v0.y);
        a[2]=(short)f2bf(v0.z); a[3]=(short)f2bf(v0.w);
        a[4]=(short)f2bf(v1.x); a[5]=(short)f2bf(v1.y);
        a[6]=(short)f2bf(v1.z); a[7]=(short)f2bf(v1.w);
        A[s] = a;
    }

    size_t baseqk[4], basev[4];
    #pragma unroll
    for (int rr = 0; rr < 4; ++rr) {
        int R  = r0 + g*4 + rr;
        int b  = R / ROWS;
        int r  = R % ROWS;
        int nh = r / 480;
        int rm = r % 480;
        int d  = rm / 24;
        int n1 = rm % 24;
        int bh = b*NH_ + nh;
        baseqk[rr] = ((size_t)bh*NN + n1*160)*HDP + d;
        basev[rr]  = ((size_t)bh*HD + d)*NN + n1*160;
    }

    const f32x4 zero4 = {0.f, 0.f, 0.f, 0.f};
    for (int nt = 0; nt < 10; ++nt) {
        const size_t wbase = (size_t)(nt*16 + c)*WW;
        f32x4 aq = zero4, ak = zero4, av = zero4;
        #pragma unroll
        for (int s = 0; s < 5; ++s) {
            s16x8 Bq = *(const s16x8*)(wqb + wbase + s*32 + g*8);
            aq = mfma32(A[s], Bq, aq);
            s16x8 Bk = *(const s16x8*)(wkb + wbase + s*32 + g*8);
            ak = mfma32(A[s], Bk, ak);
            s16x8 Bv = *(const s16x8*)(wvb + wbase + s*32 + g*8);
            av = mfma32(A[s], Bv, av);
        }
        const int o = nt*16 + c;
        const float bqv = bq[o]*LOG2E, bkv = bk[o], bvv = bv[o];
        #pragma unroll
        for (int rr = 0; rr < 4; ++rr) {
            qt[baseqk[rr] + (size_t)o*HDP] = f2bf(aq[rr] + bqv);
            kt[baseqk[rr] + (size_t)o*HDP] = f2bf(ak[rr] + bkv);
            vb[basev[rr] + o]              = f2bf(av[rr] + bvv);
        }
    }
}

// ---------------- Pass 1: zinv[m] = 1 / sum_n exp2(E[m,n]) ---------------
// R12-exact (passing): 1920 blocks, XCD swizzle, 1-deep K prefetch.
__global__ __launch_bounds__(256, 4)
void zinv_kernel(const unsigned short* __restrict__ qt,
                 const unsigned short* __restrict__ kt,
                 float* __restrict__ zinv)
{
    __shared__ float zred[4][64];
    const int blk  = ((int)blockIdx.x & 7) * (NBH*(NN/64)/8) + ((int)blockIdx.x >> 3);
    const int bh   = blk / (NN/64);
    const int m0   = (blk % (NN/64)) * 64;
    const int tid  = threadIdx.x;
    const int wv   = tid >> 6;
    const int lane = tid & 63;
    const int g = lane >> 4, c = lane & 15;

    s16x8 qa[4];
    #pragma unroll
    for (int ms = 0; ms < 4; ++ms)
        qa[ms] = *(const s16x8*)(qt + ((size_t)bh*NN + m0 + ms*16 + c)*HDP + g*8);

    const f32x4 zero4 = {0.f, 0.f, 0.f, 0.f};
    f32x4 z[4];
    #pragma unroll
    for (int ms = 0; ms < 4; ++ms) z[ms] = zero4;

    const unsigned short* kbase = kt + (size_t)bh*NN*HDP;
    const int nbeg = wv * (NN/4);
    const int nend = nbeg + NN/4;

    s16x8 kb0 = *(const s16x8*)(kbase + (size_t)(nbeg +      c)*HDP + g*8);
    s16x8 kb1 = *(const s16x8*)(kbase + (size_t)(nbeg + 16 + c)*HDP + g*8);

    for (int n = nbeg; n < nend - 32; n += 32) {
        s16x8 nk0 = *(const s16x8*)(kbase + (size_t)(n + 32 +      c)*HDP + g*8);
        s16x8 nk1 = *(const s16x8*)(kbase + (size_t)(n + 48 +      c)*HDP + g*8);
        #pragma unroll
        for (int ms = 0; ms < 4; ++ms) {
            f32x4 e0 = mfma32(qa[ms], kb0, zero4);
            f32x4 e1 = mfma32(qa[ms], kb1, zero4);
            #pragma unroll
            for (int rr = 0; rr < 4; ++rr)
                z[ms][rr] += exp2fast(e0[rr]) + exp2fast(e1[rr]);
        }
        kb0 = nk0; kb1 = nk1;
    }
    #pragma unroll
    for (int ms = 0; ms < 4; ++ms) {
        f32x4 e0 = mfma32(qa[ms], kb0, zero4);
        f32x4 e1 = mfma32(qa[ms], kb1, zero4);
        #pragma unroll
        for (int rr = 0; rr < 4; ++rr)
            z[ms][rr] += exp2fast(e0[rr]) + exp2fast(e1[rr]);
    }

    #pragma unroll
    for (int ms = 0; ms < 4; ++ms) {
        #pragma unroll
        for (int rr = 0; rr < 4; ++rr) {
            float v = z[ms][rr];
            v += __shfl_xor(v, 1);
            v += __shfl_xor(v, 2);
            v += __shfl_xor(v, 4);
            v += __shfl_xor(v, 8);
            if (c == 0) zred[wv][ms*16 + g*4 + rr] = v;
        }
    }
    __syncthreads();
    if (tid < 64) {
        float s = zred[0][tid] + zred[1][tid] + zred[2][tid] + zred[3][tid];
        zinv[(size_t)bh*NN + m0 + tid] = 1.0f / s;
    }
}

// ---------------- vzt: quad-major Vz ------------------------------------
// vzt[bh][q=m/4][dp][m%4] bf16 (256 B per m-quad). Makes attn's PV A-frag
// loads contiguous per lane-group: addr(lane g,c) = (Q+g)*128 + dp*4 elems
// -> 4 fully-used 128B segments per instr (vs 16 quarter-used with [dp][m]).
// Thread = (bh, q, dp): writes 8 B coalesced across dp; reads gather from
// L2-resident vb/zinv.
__global__ __launch_bounds__(256)
void vz_kernel(const unsigned short* __restrict__ vb,
               const float* __restrict__ zinv,
               unsigned short* __restrict__ vzt)
{
    size_t idx = (size_t)blockIdx.x*256 + threadIdx.x;   // over NBH*(NN/4)*HDP
    int dp = (int)(idx % HDP);
    size_t t = idx / HDP;
    int q  = (int)(t % (NN/4));
    int bh = (int)(t / (NN/4));
    float v0=0.f, v1=0.f, v2=0.f, v3=0.f;
    if (dp < HD) {
        const unsigned short* src = vb + ((size_t)bh*HD + dp)*NN + q*4;
        const float* zi = zinv + (size_t)bh*NN + q*4;
        v0 = bf2f(src[0])*zi[0];
        v1 = bf2f(src[1])*zi[1];
        v2 = bf2f(src[2])*zi[2];
        v3 = bf2f(src[3])*zi[3];
    }
    s16x4 o;
    o[0]=(short)f2bf(v0); o[1]=(short)f2bf(v1);
    o[2]=(short)f2bf(v2); o[3]=(short)f2bf(v3);
    *(s16x4*)(vzt + (size_t)bh*HDP*NN + (size_t)q*(HDP*4) + dp*4) = o;
}

// ---------------- Pass 2: out = Vz * exp2(Q^T K) ------------------------
// R16 delta on R15 base: Vz loads from quad-major vzt (coalesced gather fix).
// PV via K=32 mfma32 with the pi-permutation trick (no mfma16, no asm).
__global__ __launch_bounds__(256, 3)
void attn_out_kernel(const unsigned short* __restrict__ qt,
                     const unsigned short* __restrict__ kt,
                     const unsigned short* __restrict__ vzt,
                     float* __restrict__ y)
{
    __shared__ float red[3][32][64];   // 24 KB
    const int blk  = ((int)blockIdx.x & 7) * (NBH*(NN/64)/8) + ((int)blockIdx.x >> 3);
    const int bh   = blk / (NN/64);
    const int n0   = (blk % (NN/64)) * 64;
    const int tid  = threadIdx.x;
    const int wv   = tid >> 6;
    const int lane = tid & 63;
    const int g = lane >> 4, c = lane & 15;
    const int b = bh >> 3, nh = bh & 7;

    const f32x4 zero4 = {0.f, 0.f, 0.f, 0.f};
    const unsigned short* qb  = qt  + (size_t)bh*NN*HDP;
    const unsigned short* kbp = kt  + (size_t)bh*NN*HDP;
    const unsigned short* vp  = vzt + (size_t)bh*HDP*NN;

    s16x8 kb[4];
    #pragma unroll
    for (int ns = 0; ns < 4; ++ns)
        kb[ns] = *(const s16x8*)(kbp + ((size_t)(n0 + ns*16 + c))*HDP + g*8);

    f32x4 acc[2][4];
    #pragma unroll
    for (int ds = 0; ds < 2; ++ds)
        #pragma unroll
        for (int ns = 0; ns < 4; ++ns) acc[ds][ns] = zero4;

    const int mbeg = wv * (NN/4);          // 960 m per wave = 15 steps of 64
    const int mend = mbeg + NN/4;

    // current-step fragments (64 m); va[ds][j] = Vz[ds*16+c][m + j*16 + g*4 ..+3]
    // from vzt: quad Q = (m>>2) + j*4 + g; elem = Q*128 + (ds*16+c)*4
    s16x8 qa[4];
    s16x4 va[2][4];
    #pragma unroll
    for (int j = 0; j < 4; ++j)
        qa[j] = *(const s16x8*)(qb + ((size_t)(mbeg + j*16 + c))*HDP + g*8);
    #pragma unroll
    for (int ds = 0; ds < 2; ++ds)
        #pragma unroll
        for (int j = 0; j < 4; ++j)
            va[ds][j] = *(const s16x4*)(vp + (size_t)((mbeg >> 2) + j*4 + g)*(HDP*4)
                                           + (ds*16 + c)*4);

    for (int m0 = mbeg; m0 < mend - 64; m0 += 64) {
        const int m1 = m0 + 64;
        // prefetch next step
        s16x8 nqa[4];
        s16x4 nva[2][4];
        #pragma unroll
        for (int j = 0; j < 4; ++j)
            nqa[j] = *(const s16x8*)(qb + ((size_t)(m1 + j*16 + c))*HDP + g*8);
        #pragma unroll
        for (int ds = 0; ds < 2; ++ds)
            #pragma unroll
            for (int j = 0; j < 4; ++j)
                nva[ds][j] = *(const s16x4*)(vp + (size_t)((m1 >> 2) + j*4 + g)*(HDP*4)
                                                + (ds*16 + c)*4);

        #pragma unroll
        for (int ns = 0; ns < 4; ++ns) {
            f32x4 e0 = mfma32(qa[0], kb[ns], zero4);
            f32x4 e1 = mfma32(qa[1], kb[ns], zero4);
            f32x4 e2 = mfma32(qa[2], kb[ns], zero4);
            f32x4 e3 = mfma32(qa[3], kb[ns], zero4);
            s16x8 P01 = cat44(exp4_pack(e0), exp4_pack(e1));   // m0..m0+31  (pi order)
            s16x8 P23 = cat44(exp4_pack(e2), exp4_pack(e3));   // m0+32..+63 (pi order)
            acc[0][ns] = mfma32(cat44(va[0][0], va[0][1]), P01, acc[0][ns]);
            acc[0][ns] = mfma32(cat44(va[0][2], va[0][3]), P23, acc[0][ns]);
            acc[1][ns] = mfma32(cat44(va[1][0], va[1][1]), P01, acc[1][ns]);
            acc[1][ns] = mfma32(cat44(va[1][2], va[1][3]), P23, acc[1][ns]);
        }
        #pragma unroll
        for (int j = 0; j < 4; ++j) qa[j] = nqa[j];
        #pragma unroll
        for (int ds = 0; ds < 2; ++ds)
            #pragma unroll
            for (int j = 0; j < 4; ++j) va[ds][j] = nva[ds][j];
    }
    // epilogue: last 64-m step
    #pragma unroll
    for (int ns = 0; ns < 4; ++ns) {
        f32x4 e0 = mfma32(qa[0], kb[ns], zero4);
        f32x4 e1 = mfma32(qa[1], kb[ns], zero4);
        f32x4 e2 = mfma32(qa[2], kb[ns], zero4);
        f32x4 e3 = mfma32(qa[3], kb[ns], zero4);
        s16x8 P01 = cat44(exp4_pack(e0), exp4_pack(e1));
        s16x8 P23 = cat44(exp4_pack(e2), exp4_pack(e3));
        acc[0][ns] = mfma32(cat44(va[0][0], va[0][1]), P01, acc[0][ns]);
        acc[0][ns] = mfma32(cat44(va[0][2], va[0][3]), P23, acc[0][ns]);
        acc[1][ns] = mfma32(cat44(va[1][0], va[1][1]), P01, acc[1][ns]);
        acc[1][ns] = mfma32(cat44(va[1][2], va[1][3]), P23, acc[1][ns]);
    }

    float* af = (float*)acc;   // 32 contiguous f32
    if (wv > 0) {
        #pragma unroll
        for (int j = 0; j < 32; ++j) red[wv-1][j][lane] = af[j];
    }
    __syncthreads();
    if (wv == 0) {
        #pragma unroll
        for (int j = 0; j < 32; ++j)
            af[j] += red[0][j][lane] + red[1][j][lane] + red[2][j][lane];
        float* yb = y + (size_t)b * CC * HH * WW;
        #pragma unroll
        for (int ds = 0; ds < 2; ++ds) {
            #pragma unroll
            for (int ns = 0; ns < 4; ++ns) {
                #pragma unroll
                for (int rr = 0; rr < 4; ++rr) {
                    int dd = ds*16 + g*4 + rr;
                    if (dd < HD)
                        yb[((size_t)(dd*NH_ + nh))*NN + n0 + ns*16 + c] = acc[ds][ns][rr];
                }
            }
        }
    }
}

extern "C" void kernel_launch(void* const* d_in, const int* in_sizes, int n_in,
                              void* d_out, int out_size, void* d_ws, size_t ws_size,
                              hipStream_t stream)
{
    const float* x  = (const float*)d_in[0];
    const float* Wq = (const float*)d_in[1];
    const float* bq = (const float*)d_in[2];
    const float* Wk = (const float*)d_in[3];
    const float* bk = (const float*)d_in[4];
    const float* Wv = (const float*)d_in[5];
    const float* bv = (const float*)d_in[6];
    float* y = (float*)d_out;

    const size_t QT_E = (size_t)NBH * NN * HDP;      // 3,932,160 bf16
    unsigned short* qt  = (unsigned short*)d_ws;
    unsigned short* kt  = qt + QT_E;
    unsigned short* vb  = kt + QT_E;
    unsigned short* vzt = vb + (size_t)NBH * HD * NN;
    float*          zinv = (float*)(vzt + QT_E);
    unsigned short* wqb = (unsigned short*)(zinv + (size_t)NBH*NN);
    unsigned short* wkb = wqb + WW*WW;
    unsigned short* wvb = wkb + WW*WW;               // total ~29.2 MB

    hipMemsetAsync(qt, 0, 2 * QT_E * sizeof(unsigned short), stream);

    wprep_kernel<<<dim3((WW*WW + 255)/256), dim3(256), 0, stream>>>(
        Wq, Wk, Wv, wqb, wkb, wvb);
    proj_mfma_kernel<<<dim3(BB*ROWS/64), dim3(256), 0, stream>>>(
        x, wqb, wkb, wvb, bq, bk, bv, qt, kt, vb);
    zinv_kernel<<<dim3(NBH*(NN/64)), dim3(256), 0, stream>>>(qt, kt, zinv);
    vz_kernel<<<dim3((NBH*(NN/4)*HDP)/256), dim3(256), 0, stream>>>(vb, zinv, vzt);
    attn_out_kernel<<<dim3(NBH*(NN/64)), dim3(256), 0, stream>>>(qt, kt, vzt, y);
}